// Round 13
// baseline (536.754 us; speedup 1.0000x reference)
//
#include <hip/hip_runtime.h>
#include <stdint.h>

typedef unsigned short u16;
typedef unsigned int   u32;

using f32x4 = __attribute__((ext_vector_type(4))) float;
using s16x8 = __attribute__((ext_vector_type(8))) short;

#define TT 20
#define BB 32
#define SS 400
#define DD 512
#define VV 50000
#define VP2 50176   // 392*128 padded vocab

__device__ __forceinline__ float bf2f(u16 u){
  u32 x = ((u32)u) << 16;
  return __builtin_bit_cast(float, x);
}
__device__ __forceinline__ u16 f2bf(float f){
  u32 x = __builtin_bit_cast(u32, f);
  x = x + 0x7fffu + ((x >> 16) & 1u);
  return (u16)(x >> 16);
}
__device__ __forceinline__ float sigm(float x){ return 1.0f/(1.0f + __expf(-x)); }
__device__ __forceinline__ float tanh_fast(float x){
  float a = fabsf(x);
  if (a < 0.25f){ float x2 = x*x; return x + x*x2*(-0.33333334f + 0.13333334f*x2); }
  return tanhf(x);
}
__device__ __forceinline__ void gld16(const void* g, void* l){
  __builtin_amdgcn_global_load_lds((const __attribute__((address_space(1))) void*)g,
                                   (__attribute__((address_space(3))) void*)l, 16, 0, 0);
}

// ---------------- mega-prep: state/weights + W_emb cast + h_e cast + gather ----------------
__global__ __launch_bounds__(256) void k_prep(
    const float* __restrict__ W_proj,
    const float* __restrict__ W_ih,   const float* __restrict__ W_hh,
    const float* __restrict__ b_ih,   const float* __restrict__ b_hh,
    const float* __restrict__ h0,     const float* __restrict__ c0,
    const float* __restrict__ enc_W,  const float* __restrict__ dec_W,
    const float* __restrict__ W_emb,  const float* __restrict__ h_e,
    const int*   __restrict__ inputs,
    u16* __restrict__ WpT,
    u16* __restrict__ Wihs, u16* __restrict__ Whhs,
    u16* __restrict__ encWb, u16* __restrict__ decWb, float* __restrict__ bgs,
    float* __restrict__ hist, u16* __restrict__ histb, float* __restrict__ c_st,
    float* __restrict__ psE,
    u16* __restrict__ Wembb, u16* __restrict__ heb, u16* __restrict__ emba)
{
  int i = blockIdx.x*256 + threadIdx.x;
  if (i < 1280){ psE[i] = 0.0f; return; }
  i -= 1280;
  if (i < 2048){ int d = i >> 2, g = i & 3; bgs[i] = b_ih[g*512 + d] + b_hh[g*512 + d]; return; }
  i -= 2048;
  if (i < 16384){ float hv = h0[i]; hist[i] = hv; histb[i] = f2bf(hv); c_st[i] = c0[i]; return; }
  i -= 16384;
  if (i < 786432){ int j = i >> 9, k = i & 511; WpT[i] = f2bf(W_proj[k*1536 + j]); return; }
  i -= 786432;
  if (i < 1048576){ // Wihs[m'][k], m' = d*4+g
    int mp = i >> 9, k = i & 511; int d = mp >> 2, g = mp & 3;
    Wihs[i] = f2bf(W_ih[(size_t)(g*512 + d)*512 + k]); return; }
  i -= 1048576;
  if (i < 1048576){
    int mp = i >> 9, k = i & 511; int d = mp >> 2, g = mp & 3;
    Whhs[i] = f2bf(W_hh[(size_t)(g*512 + d)*512 + k]); return; }
  i -= 1048576;
  if (i < 262144){ encWb[i] = f2bf(enc_W[i]); return; }
  i -= 262144;
  if (i < 262144){ decWb[i] = f2bf(dec_W[i]); return; }
  i -= 262144;
  if (i < 6422528){ // W_emb -> bf16 with zero pad rows, 4 elems/thread
    int base = i*4;
    uint2 o;
    if (base < VV*DD){
      float4 v = *(const float4*)&W_emb[base];
      o.x = (u32)f2bf(v.x) | ((u32)f2bf(v.y) << 16);
      o.y = (u32)f2bf(v.z) | ((u32)f2bf(v.w) << 16);
    } else { o.x = 0u; o.y = 0u; }
    *(uint2*)&Wembb[base] = o;
    return; }
  i -= 6422528;
  if (i < 1638400){ // h_e -> bf16 transposed to [b][s][d]
    int base = i*4;
    const int s = base >> 14;
    const int b = (base >> 9) & 31;
    const int d = base & 511;
    float4 v = *(const float4*)&h_e[base];
    uint2 o;
    o.x = (u32)f2bf(v.x) | ((u32)f2bf(v.y) << 16);
    o.y = (u32)f2bf(v.z) | ((u32)f2bf(v.w) << 16);
    *(uint2*)&heb[((size_t)(b*SS + s) << 9) + d] = o;
    return; }
  i -= 1638400;
  if (i < 81920){ // gather embeddings from fp32 W_emb
    int base = i*4;
    int r = base >> 9, k = base & 511;
    float4 v = *(const float4*)&W_emb[(size_t)inputs[r]*DD + k];
    uint2 o;
    o.x = (u32)f2bf(v.x) | ((u32)f2bf(v.y) << 16);
    o.y = (u32)f2bf(v.z) | ((u32)f2bf(v.w) << 16);
    *(uint2*)&emba[base] = o;
    return; }
}

// ---------------- 128x128 GEMM tile, BK=64, swizzled 128B rows ----------------
// LDS: As/Bs 128 rows x 64 u16; chunk16 swizzle c' = c ^ (row&7). Peak LDS 32 KB (5 blk/CU).
// EPI: 0 = fp32 out (direct), 1 = tanh->bf16 (2-half repack), 3 = bf16+bias col<nmax (2-half repack)
template<int EPI>
__device__ __forceinline__ void gemm_tile(
    const u16* __restrict__ A, const u16* __restrict__ B,
    float* __restrict__ Cf, u16* __restrict__ Cb, const float* __restrict__ bias,
    int K, int mt, int nt, int ldc, int nmax, char* smemc)
{
  u16* As = (u16*)smemc;             // 16 KB
  u16* Bs = (u16*)(smemc + 16384);   // 16 KB
  const int tid = threadIdx.x;
  const int w = tid >> 6, l = tid & 63;
  const int m0 = mt*128, n0 = nt*128;
  const int srow = tid >> 3;
  const int scol = ((tid & 7) ^ ((tid >> 3) & 7)) * 8;
  const int wm = (w >> 1)*64, wn = (w & 1)*64;
  const int fr = l & 15;
  const int g4 = l >> 4;
  float bv[4];
  if constexpr (EPI == 3){
    #pragma unroll
    for (int j = 0; j < 4; ++j){
      const int c = n0 + wn + j*16 + fr;
      bv[j] = (c < nmax) ? bias[c] : 0.0f;
    }
  }
  f32x4 acc[4][4] = {};
  for (int k0 = 0; k0 < K; k0 += 64){
    #pragma unroll
    for (int j = 0; j < 4; ++j){
      gld16(A + (size_t)(m0 + j*32 + srow)*K + k0 + scol, (char*)As + j*4096 + (w << 10));
      gld16(B + (size_t)(n0 + j*32 + srow)*K + k0 + scol, (char*)Bs + j*4096 + (w << 10));
    }
    __syncthreads();
    #pragma unroll
    for (int h = 0; h < 2; ++h){
      s16x8 af[4], bfr[4];
      #pragma unroll
      for (int i = 0; i < 4; ++i){
        const int ra = wm + i*16 + fr;
        af[i]  = *(const s16x8*)((char*)As + ra*128 + ((((h << 2) + g4) ^ (ra & 7)) << 4));
        const int rb = wn + i*16 + fr;
        bfr[i] = *(const s16x8*)((char*)Bs + rb*128 + ((((h << 2) + g4) ^ (rb & 7)) << 4));
      }
      #pragma unroll
      for (int i = 0; i < 4; ++i)
        #pragma unroll
        for (int j2 = 0; j2 < 4; ++j2)
          acc[i][j2] = __builtin_amdgcn_mfma_f32_16x16x32_bf16(af[i], bfr[j2], acc[i][j2], 0, 0, 0);
    }
    __syncthreads();
  }
  if constexpr (EPI == 0){
    #pragma unroll
    for (int i = 0; i < 4; ++i)
      #pragma unroll
      for (int j = 0; j < 4; ++j)
        #pragma unroll
        for (int r = 0; r < 4; ++r){
          const int row = m0 + wm + i*16 + (l >> 4)*4 + r;
          const int col = n0 + wn + j*16 + fr;
          Cf[(size_t)row*ldc + col] = acc[i][j][r];
        }
  } else {
    // 2-half repack through 64x136 Rs (17.4 KB) -> peak LDS stays 32 KB
    u16* Rs = (u16*)smemc;
    #pragma unroll
    for (int half = 0; half < 2; ++half){
      if ((w >> 1) == half){
        #pragma unroll
        for (int i = 0; i < 4; ++i){
          #pragma unroll
          for (int j = 0; j < 4; ++j){
            #pragma unroll
            for (int r = 0; r < 4; ++r){
              const int rl = (wm - half*64) + i*16 + (l >> 4)*4 + r;   // 0..63
              const int cl = wn + j*16 + fr;
              const float v = acc[i][j][r];
              u16 o;
              if constexpr (EPI == 1) o = f2bf(tanh_fast(v));
              else                    o = f2bf(v + bv[j]);
              Rs[rl*136 + cl] = o;
            }
          }
        }
      }
      __syncthreads();
      const int rr0 = tid >> 4;        // 0..15
      const int cb  = (tid & 15)*8;
      #pragma unroll
      for (int p = 0; p < 4; ++p){
        const int row = p*16 + rr0;    // 0..63
        const int gc  = n0 + cb;
        s16x8 val = *(const s16x8*)&Rs[row*136 + cb];
        u16* dst = Cb + (size_t)(m0 + half*64 + row)*ldc + gc;
        if (EPI == 1 || gc + 8 <= nmax){
          *(s16x8*)dst = val;
        } else {
          #pragma unroll
          for (int q = 0; q < 8; ++q)
            if (gc + q < nmax) dst[q] = (u16)val[q];
        }
      }
      __syncthreads();
    }
  }
}

template<int EPI, int ORD>
__global__ __launch_bounds__(256) void gemm_bt(
    const u16* __restrict__ A, const u16* __restrict__ B,
    float* __restrict__ Cf, u16* __restrict__ Cb, const float* __restrict__ bias,
    int K, int TM, int TN, int ldc, int nmax)
{
  __shared__ __align__(16) char smem[32768];
  int bid = blockIdx.x;
  if (ORD >= 1){
    const int n = TM*TN, x = bid & 7, i = bid >> 3;
    const int q = n >> 3, r = n & 7;
    bid = (x < r ? x*(q+1) : r*(q+1) + (x-r)*q) + i;
  }
  const int mt = (ORD == 1) ? bid / TN : bid % TM;
  const int nt = (ORD == 1) ? bid % TN : bid / TM;
  gemm_tile<EPI>(A, B, Cf, Cb, bias, K, mt, nt, ldc, nmax, smem);
}

// ---------------- LSTM chain step: gates MFMA + cell (grid 128) ----------------
__global__ __launch_bounds__(256) void k_lstm(
    const u16* __restrict__ Whhs, const float* __restrict__ X, const float* __restrict__ bgs,
    float* __restrict__ hist, u16* __restrict__ histb, float* __restrict__ c_st,
    u16* __restrict__ ccatb, int t)
{
  __shared__ __align__(16) u16 Hs[32*512];
  __shared__ __align__(16) u16 As[16*512];
  __shared__ float Cp[4][16][32];
  const int blk = blockIdx.x;
  const int tid = threadIdx.x;
  const int w = tid >> 6, l = tid & 63;
  const char* hsrc = (const char*)(histb + (size_t)t*16384);
  #pragma unroll
  for (int p = 0; p < 8; ++p)
    gld16(hsrc + p*4096 + w*1024 + l*16, (char*)Hs + p*4096 + w*1024);
  const char* asrc = (const char*)(Whhs + (size_t)blk*16*512);
  #pragma unroll
  for (int p = 0; p < 4; ++p)
    gld16(asrc + p*4096 + w*1024 + l*16, (char*)As + p*4096 + w*1024);
  __syncthreads();
  {
    const int fr = l & 15, fko = (l >> 4)*8;
    f32x4 acc0 = {}, acc1 = {};
    #pragma unroll
    for (int kk = 0; kk < 4; ++kk){
      const int kb = (w*4 + kk)*32;
      s16x8 af = *(const s16x8*)&As[fr*512 + kb + fko];
      s16x8 b0 = *(const s16x8*)&Hs[fr*512 + kb + fko];
      s16x8 b1 = *(const s16x8*)&Hs[(16 + fr)*512 + kb + fko];
      acc0 = __builtin_amdgcn_mfma_f32_16x16x32_bf16(af, b0, acc0, 0, 0, 0);
      acc1 = __builtin_amdgcn_mfma_f32_16x16x32_bf16(af, b1, acc1, 0, 0, 0);
    }
    #pragma unroll
    for (int r = 0; r < 4; ++r){
      Cp[w][(l >> 4)*4 + r][fr]      = acc0[r];
      Cp[w][(l >> 4)*4 + r][16 + fr] = acc1[r];
    }
  }
  __syncthreads();
  if (tid < 128){
    const int dl = tid >> 5, b = tid & 31;
    const int d = blk*4 + dl;
    const int bd = b*512 + d;
    float gv[4];
    #pragma unroll
    for (int g = 0; g < 4; ++g)
      gv[g] = Cp[0][dl*4 + g][b] + Cp[1][dl*4 + g][b] + Cp[2][dl*4 + g][b] + Cp[3][dl*4 + g][b];
    const float4 x4 = *(const float4*)&X[((size_t)(t*BB + b))*2048 + d*4];
    const float4 g4 = *(const float4*)&bgs[d*4];
    const float iv = gv[0] + x4.x + g4.x;
    const float fv = gv[1] + x4.y + g4.y;
    const float gg = gv[2] + x4.z + g4.z;
    const float ov = gv[3] + x4.w + g4.w;
    const float cn = sigm(fv)*c_st[bd] + sigm(iv)*tanhf(gg);
    const float hd = sigm(ov)*tanhf(cn);
    c_st[bd] = cn;
    hist[(size_t)(t + 1)*16384 + bd] = hd;
    const u16 hb = f2bf(hd);
    histb[(size_t)(t + 1)*16384 + bd] = hb;
    ccatb[((size_t)(t*BB + b))*1536 + d] = hb;
  }
}

// ---------------- bulk QE/QD ----------------
__global__ __launch_bounds__(256) void k_bulkq(
    const u16* __restrict__ Hb, const u16* __restrict__ encWb, const u16* __restrict__ decWb,
    float* __restrict__ qe_all, float* __restrict__ qd_all)
{
  __shared__ __align__(16) char smem[32768];
  const int e = blockIdx.x;           // 0..39
  const int which = e / 20;
  const int e2 = e % 20;
  const int mt = e2 % 5, nt = e2 / 5;
  gemm_tile<0>(Hb, which ? decWb : encWb, which ? qd_all : qe_all,
               nullptr, nullptr, 512, mt, nt, 512, 0, smem);
}

// ---------------- bulk attention: 640 enc rows + 640 dec rows ----------------
__global__ __launch_bounds__(256) void k_attn(
    const u16* __restrict__ heb, const float* __restrict__ hist,
    const float* __restrict__ qe_all, const float* __restrict__ qd_all,
    const float* __restrict__ puW,
    u16* __restrict__ ccatb, float* __restrict__ aeall,
    float* __restrict__ psE, float* __restrict__ psD)
{
  __shared__ float hcur[512];
  __shared__ float qv[512];
  __shared__ float ael[SS];
  __shared__ float red[256];
  __shared__ float part[4*512];
  __shared__ float adl[TT];
  __shared__ float sdl[TT];
  __shared__ float shs[2];
  const int blk = blockIdx.x;
  const int tid = threadIdx.x;

  if (blk < 640){
    const int row = blk;
    const int t = row >> 5, b = row & 31;
    const float* hsrc = hist + (size_t)(t + 1)*16384 + b*512;
    const float* qsrc = qe_all + (size_t)row*512;
    hcur[tid] = hsrc[tid]; hcur[tid + 256] = hsrc[tid + 256];
    qv[tid] = qsrc[tid];   qv[tid + 256] = qsrc[tid + 256];
    __syncthreads();
    for (int pass = 0; pass < 7; ++pass){
      const int s = pass*64 + (tid >> 2);
      if (s < SS){
        const u16* gp = heb + ((size_t)(b*SS + s))*512 + (tid & 3)*128;
        const float* hp = qv + (tid & 3)*128;
        float p = 0.0f;
        #pragma unroll 4
        for (int k8 = 0; k8 < 128; k8 += 8){
          s16x8 g8 = *(const s16x8*)&gp[k8];
          #pragma unroll
          for (int q = 0; q < 8; ++q) p += bf2f((u16)g8[q])*hp[k8 + q];
        }
        p += __shfl_xor(p, 1); p += __shfl_xor(p, 2);
        if ((tid & 3) == 0) ael[s] = p;
      }
    }
    __syncthreads();
    float lm = -1e30f;
    for (int s = tid; s < SS; s += 256) lm = fmaxf(lm, ael[s]);
    red[tid] = lm; __syncthreads();
    for (int st = 128; st; st >>= 1){ if (tid < st) red[tid] = fmaxf(red[tid], red[tid + st]); __syncthreads(); }
    const float M = red[0]; __syncthreads();
    float ls = 0.0f;
    for (int s = tid; s < SS; s += 256){ float p = __expf(ael[s] - M); ael[s] = p; ls += p; }
    red[tid] = ls; __syncthreads();
    for (int st = 128; st; st >>= 1){ if (tid < st) red[tid] += red[tid + st]; __syncthreads(); }
    const float inv = 1.0f/red[0];
    __syncthreads();
    {
      const int g = tid >> 6, th = tid & 63;
      const int d0 = th*8;
      float a8[8] = {};
      for (int s = g; s < SS; s += 4){
        const float a = ael[s];
        s16x8 hv = *(const s16x8*)&heb[((size_t)(b*SS + s))*512 + d0];
        #pragma unroll
        for (int q = 0; q < 8; ++q) a8[q] += a*bf2f((u16)hv[q]);
      }
      *(float4*)&part[g*512 + d0]     = float4{a8[0], a8[1], a8[2], a8[3]};
      *(float4*)&part[g*512 + d0 + 4] = float4{a8[4], a8[5], a8[6], a8[7]};
    }
    __syncthreads();
    {
      const int dd = tid*2;
      float ce0 = part[dd]     + part[512 + dd]     + part[1024 + dd]     + part[1536 + dd];
      float ce1 = part[dd + 1] + part[512 + dd + 1] + part[1024 + dd + 1] + part[1536 + dd + 1];
      ce0 *= inv; ce1 *= inv;
      *(u32*)&ccatb[(size_t)row*1536 + 512 + dd] = (u32)f2bf(ce0) | ((u32)f2bf(ce1) << 16);
      float pv = hcur[dd]*puW[dd] + hcur[dd + 1]*puW[dd + 1]
               + ce0*puW[512 + dd] + ce1*puW[512 + dd + 1];
      red[tid] = pv;
    }
    __syncthreads();
    for (int st = 128; st; st >>= 1){ if (tid < st) red[tid] += red[tid + st]; __syncthreads(); }
    if (tid == 0) psE[row] = red[0];
    for (int s = tid; s < SS; s += 256) aeall[(size_t)row*SS + s] = ael[s]*inv;
  } else {
    const int row = blk - 640;
    const int t = row >> 5, b = row & 31;
    const float* qsrc = qd_all + (size_t)row*512;
    qv[tid] = qsrc[tid]; qv[tid + 256] = qsrc[tid + 256];
    __syncthreads();
    for (int u0 = 0; u0 < t; u0 += 8){
      const int u = u0 + (tid >> 5);
      if (u < t){
        const float* hu = hist + (size_t)(u + 1)*16384 + b*512;
        float p = 0.0f;
        #pragma unroll
        for (int j = 0; j < 4; ++j){
          const int kb = (tid & 31)*4 + j*128;
          const float4 h4 = *(const float4*)&hu[kb];
          const float4 q4 = *(const float4*)&qv[kb];
          p += h4.x*q4.x + h4.y*q4.y + h4.z*q4.z + h4.w*q4.w;
        }
        p += __shfl_xor(p, 1); p += __shfl_xor(p, 2); p += __shfl_xor(p, 4);
        p += __shfl_xor(p, 8); p += __shfl_xor(p, 16);
        if ((tid & 31) == 0) sdl[u] = p;
      }
    }
    __syncthreads();
    if (tid == 0 && t > 0){
      float m2 = -1e30f;
      for (int u = 0; u < t; ++u) m2 = fmaxf(m2, sdl[u]);
      float s2 = 0.0f;
      for (int u = 0; u < t; ++u){ float p = __expf(sdl[u] - m2); adl[u] = p; s2 += p; }
      shs[0] = 1.0f/s2;
    }
    __syncthreads();
    const float invd = (t > 0) ? shs[0] : 0.0f;
    const int d0 = tid*2;
    float e0 = 0.0f, e1 = 0.0f;
    for (int u = 0; u < t; ++u){
      const float a = adl[u];
      const float* hu = hist + (size_t)(u + 1)*16384 + b*512 + d0;
      e0 += a*hu[0]; e1 += a*hu[1];
    }
    e0 *= invd; e1 *= invd;
    *(u32*)&ccatb[(size_t)row*1536 + 1024 + d0] = (u32)f2bf(e0) | ((u32)f2bf(e1) << 16);
    float pv = e0*puW[1024 + d0] + e1*puW[1024 + d0 + 1];
    red[tid] = pv; __syncthreads();
    for (int st = 128; st; st >>= 1){ if (tid < st) red[tid] += red[tid + st]; __syncthreads(); }
    if (tid == 0) psD[row] = red[0];
  }
}

// ---------------- vocab softmax (max-free, bf16 logits stride VP2) + fused scatter ----------------
// |logit| is bounded to a few units (ccat in [-1,1], W_out=tanh(small), b_out small),
// so exp without max subtraction is numerically safe (validated rounds 12).
__global__ __launch_bounds__(256) void k_softmax(
    const u16* __restrict__ lg, float* __restrict__ out,
    const float* __restrict__ psE, const float* __restrict__ psD, const float* __restrict__ puB,
    const int* __restrict__ src, const float* __restrict__ ae_all)
{
  const int r = blockIdx.x, tid = threadIdx.x;
  __shared__ float rs[256];
  __shared__ float sh_inv, sh_ps;
  const u16* row = lg + (size_t)r*VP2;
  float s = 0.0f;
  for (int v8 = tid*8; v8 < VV; v8 += 2048){
    uint4 pk = *(const uint4*)&row[v8];
    u32 wds[4] = {pk.x, pk.y, pk.z, pk.w};
    #pragma unroll
    for (int q = 0; q < 8; ++q)
      s += __expf(bf2f((u16)((wds[q >> 1] >> ((q & 1)*16)) & 0xffffu)));
  }
  rs[tid] = s; __syncthreads();
  for (int st = 128; st; st >>= 1){ if (tid < st) rs[tid] += rs[tid + st]; __syncthreads(); }
  if (tid == 0){
    const float ps = 1.0f/(1.0f + __expf(-(psE[r] + psD[r] + puB[0])));
    const float stot = rs[0] - __expf(bf2f(row[1]));   // exclude PAD
    sh_ps = ps;
    sh_inv = (1.0f - ps)/stot;
  }
  __syncthreads();
  const float inv = sh_inv;
  const float ps = sh_ps;
  float* orow = out + (size_t)r*VV;
  for (int v8 = tid*8; v8 < VV; v8 += 2048){
    uint4 pk = *(const uint4*)&row[v8];
    u32 wds[4] = {pk.x, pk.y, pk.z, pk.w};
    float o[8];
    #pragma unroll
    for (int q = 0; q < 8; ++q)
      o[q] = __expf(bf2f((u16)((wds[q >> 1] >> ((q & 1)*16)) & 0xffffu)))*inv;
    *(float4*)&orow[v8]     = float4{o[0], o[1], o[2], o[3]};
    *(float4*)&orow[v8 + 4] = float4{o[4], o[5], o[6], o[7]};
  }
  if (tid == 0) orow[1] = 0.0f;      // PAD masked before scatter
  __syncthreads();
  // fused copy-distribution scatter into this block's own row (L2-hot)
  const int b = r & 31;
  for (int sp = tid; sp < SS; sp += 256){
    const int v = src[sp*BB + b];
    atomicAdd(&orow[v], ae_all[(size_t)r*SS + sp]*ps);
  }
}

extern "C" void kernel_launch(void* const* d_in, const int* in_sizes, int n_in,
                              void* d_out, int out_size, void* d_ws, size_t ws_size,
                              hipStream_t stream)
{
  const int*   inputs = (const int*)  d_in[0];
  const int*   src    = (const int*)  d_in[1];
  const float* h_e    = (const float*)d_in[2];
  const float* h0     = (const float*)d_in[3];
  const float* c0     = (const float*)d_in[4];
  const float* W_emb  = (const float*)d_in[5];
  const float* W_proj = (const float*)d_in[6];
  const float* b_out  = (const float*)d_in[7];
  const float* puW    = (const float*)d_in[8];
  const float* puB    = (const float*)d_in[9];
  const float* enc_W  = (const float*)d_in[10];
  const float* dec_W  = (const float*)d_in[11];
  const float* W_ih   = (const float*)d_in[12];
  const float* W_hh   = (const float*)d_in[13];
  const float* b_ih   = (const float*)d_in[14];
  const float* b_hh   = (const float*)d_in[15];
  float* out = (float*)d_out;

  char* wp = (char*)d_ws;
  auto alloc = [&](size_t bytes) -> char* {
    char* p = wp; wp += (bytes + 255) & ~(size_t)255; return p;
  };
  // Early-dead region (reclaimed for bf16 logits after k_attn):
  u16*   Wembb = (u16*)  alloc((size_t)VP2*DD*2);     // dead after W_out GEMM
  u16*   WpT   = (u16*)  alloc(1536*512*2);           // dead after W_out GEMM
  u16*   heb   = (u16*)  alloc((size_t)SS*BB*DD*2);   // dead after k_attn
  u16*   logitsb = (u16*)Wembb;                       // 640*VP2*2 = 64.2MB <= 66.0MB above
  // Long-lived:
  u16*   Woutb = (u16*)  alloc((size_t)VP2*1536*2);
  u16*   Wihs  = (u16*)  alloc(2048*512*2);
  u16*   Whhs  = (u16*)  alloc(2048*512*2);
  u16*   encWb = (u16*)  alloc(512*512*2);
  u16*   decWb = (u16*)  alloc(512*512*2);
  float* bgs   = (float*)alloc(2048*4);
  u16*   emba  = (u16*)  alloc((size_t)TT*BB*DD*2);
  float* X     = (float*)alloc((size_t)TT*BB*2048*4);
  float* c_st  = (float*)alloc(BB*DD*4);
  float* hist  = (float*)alloc((size_t)(TT+1)*BB*DD*4);
  u16*   histb = (u16*)  alloc((size_t)(TT+1)*BB*DD*2);
  u16*   ccatb = (u16*)  alloc((size_t)TT*BB*1536*2);
  float* aeall = (float*)alloc((size_t)TT*BB*SS*4);
  float* psE   = (float*)alloc(1280*4);
  float* psD   = psE + 640;
  float* qe_all= (float*)alloc((size_t)TT*BB*DD*4);
  float* qd_all= (float*)alloc((size_t)TT*BB*DD*4);

  // mega-prep
  k_prep<<<45197, 256, 0, stream>>>(W_proj, W_ih, W_hh, b_ih, b_hh, h0, c0, enc_W, dec_W,
                                    W_emb, h_e, inputs,
                                    WpT, Wihs, Whhs, encWb, decWb, bgs, hist, histb, c_st, psE,
                                    Wembb, heb, emba);

  // X = emb @ W_ih^T
  gemm_bt<0,0><<<5*16, 256, 0, stream>>>(emba, Wihs, X, nullptr, nullptr, 512, 5, 16, 2048, 0);

  // W_out = tanh(W_emb @ W_proj): 128^2 BK=64 tiles, nt-fastest for A reuse
  gemm_bt<1,1><<<392*12, 256, 0, stream>>>(Wembb, WpT, nullptr, Woutb, nullptr, 512, 392, 12, 1536, 0);

  // sequential LSTM chain
  for (int t = 0; t < TT; ++t)
    k_lstm<<<128, 256, 0, stream>>>(Whhs, X, bgs, hist, histb, c_st, ccatb, t);

  // bulk attention
  k_bulkq<<<40, 256, 0, stream>>>(histb + 16384, encWb, decWb, qe_all, qd_all);
  k_attn<<<1280, 256, 0, stream>>>(heb, hist, qe_all, qd_all, puW, ccatb, aeall, psE, psD);

  // logits = ccat @ W_out^T + b_out (mt-fastest)
  gemm_bt<3,2><<<5*392, 256, 0, stream>>>(ccatb, Woutb, nullptr, logitsb, b_out, 1536, 5, 392, VP2, VV);

  // softmax + fused scatter
  k_softmax<<<TT*BB, 256, 0, stream>>>(logitsb, out, psE, psD, puB, src, aeall);
}

// Round 14
// 492.719 us; speedup vs baseline: 1.0894x; 1.0894x over previous
//
#include <hip/hip_runtime.h>
#include <stdint.h>

typedef unsigned short u16;
typedef unsigned int   u32;

using f32x4 = __attribute__((ext_vector_type(4))) float;
using s16x8 = __attribute__((ext_vector_type(8))) short;

#define TT 20
#define BB 32
#define SS 400
#define DD 512
#define VV 50000
#define VP2 50176   // 392*128 padded vocab

__device__ __forceinline__ float bf2f(u16 u){
  u32 x = ((u32)u) << 16;
  return __builtin_bit_cast(float, x);
}
__device__ __forceinline__ u16 f2bf(float f){
  u32 x = __builtin_bit_cast(u32, f);
  x = x + 0x7fffu + ((x >> 16) & 1u);
  return (u16)(x >> 16);
}
__device__ __forceinline__ float sigm(float x){ return 1.0f/(1.0f + __expf(-x)); }
__device__ __forceinline__ float tanh_fast(float x){
  float a = fabsf(x);
  if (a < 0.25f){ float x2 = x*x; return x + x*x2*(-0.33333334f + 0.13333334f*x2); }
  return tanhf(x);
}
__device__ __forceinline__ void gld16(const void* g, void* l){
  __builtin_amdgcn_global_load_lds((const __attribute__((address_space(1))) void*)g,
                                   (__attribute__((address_space(3))) void*)l, 16, 0, 0);
}

// ---------------- mega-prep: state/weights + W_emb cast + h_e cast + gather ----------------
__global__ __launch_bounds__(256) void k_prep(
    const float* __restrict__ W_proj,
    const float* __restrict__ W_ih,   const float* __restrict__ W_hh,
    const float* __restrict__ b_ih,   const float* __restrict__ b_hh,
    const float* __restrict__ h0,     const float* __restrict__ c0,
    const float* __restrict__ enc_W,  const float* __restrict__ dec_W,
    const float* __restrict__ W_emb,  const float* __restrict__ h_e,
    const int*   __restrict__ inputs,
    u16* __restrict__ WpT,
    u16* __restrict__ Wihs, u16* __restrict__ Whhs,
    u16* __restrict__ encWb, u16* __restrict__ decWb, float* __restrict__ bgs,
    float* __restrict__ hist, u16* __restrict__ histb, float* __restrict__ c_st,
    float* __restrict__ psE,
    u16* __restrict__ Wembb, u16* __restrict__ heb, u16* __restrict__ emba)
{
  int i = blockIdx.x*256 + threadIdx.x;
  if (i < 1280){ psE[i] = 0.0f; return; }
  i -= 1280;
  if (i < 2048){ int d = i >> 2, g = i & 3; bgs[i] = b_ih[g*512 + d] + b_hh[g*512 + d]; return; }
  i -= 2048;
  if (i < 16384){ float hv = h0[i]; hist[i] = hv; histb[i] = f2bf(hv); c_st[i] = c0[i]; return; }
  i -= 16384;
  if (i < 786432){ int j = i >> 9, k = i & 511; WpT[i] = f2bf(W_proj[k*1536 + j]); return; }
  i -= 786432;
  if (i < 1048576){ // Wihs[m'][k], m' = d*4+g
    int mp = i >> 9, k = i & 511; int d = mp >> 2, g = mp & 3;
    Wihs[i] = f2bf(W_ih[(size_t)(g*512 + d)*512 + k]); return; }
  i -= 1048576;
  if (i < 1048576){
    int mp = i >> 9, k = i & 511; int d = mp >> 2, g = mp & 3;
    Whhs[i] = f2bf(W_hh[(size_t)(g*512 + d)*512 + k]); return; }
  i -= 1048576;
  if (i < 262144){ encWb[i] = f2bf(enc_W[i]); return; }
  i -= 262144;
  if (i < 262144){ decWb[i] = f2bf(dec_W[i]); return; }
  i -= 262144;
  if (i < 6422528){ // W_emb -> bf16 with zero pad rows, 4 elems/thread
    int base = i*4;
    uint2 o;
    if (base < VV*DD){
      float4 v = *(const float4*)&W_emb[base];
      o.x = (u32)f2bf(v.x) | ((u32)f2bf(v.y) << 16);
      o.y = (u32)f2bf(v.z) | ((u32)f2bf(v.w) << 16);
    } else { o.x = 0u; o.y = 0u; }
    *(uint2*)&Wembb[base] = o;
    return; }
  i -= 6422528;
  if (i < 1638400){ // h_e -> bf16 transposed to [b][s][d]
    int base = i*4;
    const int s = base >> 14;
    const int b = (base >> 9) & 31;
    const int d = base & 511;
    float4 v = *(const float4*)&h_e[base];
    uint2 o;
    o.x = (u32)f2bf(v.x) | ((u32)f2bf(v.y) << 16);
    o.y = (u32)f2bf(v.z) | ((u32)f2bf(v.w) << 16);
    *(uint2*)&heb[((size_t)(b*SS + s) << 9) + d] = o;
    return; }
  i -= 1638400;
  if (i < 81920){ // gather embeddings from fp32 W_emb
    int base = i*4;
    int r = base >> 9, k = base & 511;
    float4 v = *(const float4*)&W_emb[(size_t)inputs[r]*DD + k];
    uint2 o;
    o.x = (u32)f2bf(v.x) | ((u32)f2bf(v.y) << 16);
    o.y = (u32)f2bf(v.z) | ((u32)f2bf(v.w) << 16);
    *(uint2*)&emba[base] = o;
    return; }
}

// ---------------- 128x128 GEMM tile, BK=64, swizzled 128B rows (round-11 champion) ----------------
// LDS: As/Bs 128 rows x 64 u16; chunk16 swizzle c' = c ^ (row&7).
// EPI: 0 = fp32 out (direct), 1 = tanh->bf16 (repack), 3 = bf16+bias col<nmax (repack)
template<int EPI>
__device__ __forceinline__ void gemm_tile(
    const u16* __restrict__ A, const u16* __restrict__ B,
    float* __restrict__ Cf, u16* __restrict__ Cb, const float* __restrict__ bias,
    int K, int mt, int nt, int ldc, int nmax, char* smemc)
{
  u16* As = (u16*)smemc;             // 16 KB
  u16* Bs = (u16*)(smemc + 16384);   // 16 KB
  const int tid = threadIdx.x;
  const int w = tid >> 6, l = tid & 63;
  const int m0 = mt*128, n0 = nt*128;
  const int srow = tid >> 3;
  const int scol = ((tid & 7) ^ ((tid >> 3) & 7)) * 8;
  const int wm = (w >> 1)*64, wn = (w & 1)*64;
  const int fr = l & 15;
  const int g4 = l >> 4;
  float bv[4];
  if constexpr (EPI == 3){
    #pragma unroll
    for (int j = 0; j < 4; ++j){
      const int c = n0 + wn + j*16 + fr;
      bv[j] = (c < nmax) ? bias[c] : 0.0f;
    }
  }
  f32x4 acc[4][4] = {};
  for (int k0 = 0; k0 < K; k0 += 64){
    #pragma unroll
    for (int j = 0; j < 4; ++j){
      gld16(A + (size_t)(m0 + j*32 + srow)*K + k0 + scol, (char*)As + j*4096 + (w << 10));
      gld16(B + (size_t)(n0 + j*32 + srow)*K + k0 + scol, (char*)Bs + j*4096 + (w << 10));
    }
    __syncthreads();
    #pragma unroll
    for (int h = 0; h < 2; ++h){
      s16x8 af[4], bfr[4];
      #pragma unroll
      for (int i = 0; i < 4; ++i){
        const int ra = wm + i*16 + fr;
        af[i]  = *(const s16x8*)((char*)As + ra*128 + ((((h << 2) + g4) ^ (ra & 7)) << 4));
        const int rb = wn + i*16 + fr;
        bfr[i] = *(const s16x8*)((char*)Bs + rb*128 + ((((h << 2) + g4) ^ (rb & 7)) << 4));
      }
      #pragma unroll
      for (int i = 0; i < 4; ++i)
        #pragma unroll
        for (int j2 = 0; j2 < 4; ++j2)
          acc[i][j2] = __builtin_amdgcn_mfma_f32_16x16x32_bf16(af[i], bfr[j2], acc[i][j2], 0, 0, 0);
    }
    __syncthreads();
  }
  if constexpr (EPI == 0){
    #pragma unroll
    for (int i = 0; i < 4; ++i)
      #pragma unroll
      for (int j = 0; j < 4; ++j)
        #pragma unroll
        for (int r = 0; r < 4; ++r){
          const int row = m0 + wm + i*16 + (l >> 4)*4 + r;
          const int col = n0 + wn + j*16 + fr;
          Cf[(size_t)row*ldc + col] = acc[i][j][r];
        }
  } else {
    u16* Rs = (u16*)smemc;   // 128*136*2 = 34816 B
    #pragma unroll
    for (int i = 0; i < 4; ++i){
      #pragma unroll
      for (int j = 0; j < 4; ++j){
        #pragma unroll
        for (int r = 0; r < 4; ++r){
          const int rl = wm + i*16 + (l >> 4)*4 + r;
          const int cl = wn + j*16 + fr;
          const float v = acc[i][j][r];
          u16 o;
          if constexpr (EPI == 1) o = f2bf(tanh_fast(v));
          else                    o = f2bf(v + bv[j]);
          Rs[rl*136 + cl] = o;
        }
      }
    }
    __syncthreads();
    const int rr0 = tid >> 4;
    const int cb  = (tid & 15)*8;
    #pragma unroll
    for (int p = 0; p < 8; ++p){
      const int row = p*16 + rr0;
      const int gc  = n0 + cb;
      s16x8 val = *(const s16x8*)&Rs[row*136 + cb];
      u16* dst = Cb + (size_t)(m0 + row)*ldc + gc;
      if (EPI == 1 || gc + 8 <= nmax){
        *(s16x8*)dst = val;
      } else {
        #pragma unroll
        for (int q = 0; q < 8; ++q)
          if (gc + q < nmax) dst[q] = (u16)val[q];
      }
    }
  }
}

template<int EPI, int ORD>
__global__ __launch_bounds__(256) void gemm_bt(
    const u16* __restrict__ A, const u16* __restrict__ B,
    float* __restrict__ Cf, u16* __restrict__ Cb, const float* __restrict__ bias,
    int K, int TM, int TN, int ldc, int nmax)
{
  __shared__ __align__(16) char smem[34816];
  int bid = blockIdx.x;
  if (ORD >= 1){
    const int n = TM*TN, x = bid & 7, i = bid >> 3;
    const int q = n >> 3, r = n & 7;
    bid = (x < r ? x*(q+1) : r*(q+1) + (x-r)*q) + i;
  }
  const int mt = (ORD == 1) ? bid / TN : bid % TM;
  const int nt = (ORD == 1) ? bid % TN : bid / TM;
  gemm_tile<EPI>(A, B, Cf, Cb, bias, K, mt, nt, ldc, nmax, smem);
}

// ---------------- LSTM chain step: gates MFMA + cell (grid 128) ----------------
__global__ __launch_bounds__(256) void k_lstm(
    const u16* __restrict__ Whhs, const float* __restrict__ X, const float* __restrict__ bgs,
    float* __restrict__ hist, u16* __restrict__ histb, float* __restrict__ c_st,
    u16* __restrict__ ccatb, int t)
{
  __shared__ __align__(16) u16 Hs[32*512];
  __shared__ __align__(16) u16 As[16*512];
  __shared__ float Cp[4][16][32];
  const int blk = blockIdx.x;
  const int tid = threadIdx.x;
  const int w = tid >> 6, l = tid & 63;
  const char* hsrc = (const char*)(histb + (size_t)t*16384);
  #pragma unroll
  for (int p = 0; p < 8; ++p)
    gld16(hsrc + p*4096 + w*1024 + l*16, (char*)Hs + p*4096 + w*1024);
  const char* asrc = (const char*)(Whhs + (size_t)blk*16*512);
  #pragma unroll
  for (int p = 0; p < 4; ++p)
    gld16(asrc + p*4096 + w*1024 + l*16, (char*)As + p*4096 + w*1024);
  __syncthreads();
  {
    const int fr = l & 15, fko = (l >> 4)*8;
    f32x4 acc0 = {}, acc1 = {};
    #pragma unroll
    for (int kk = 0; kk < 4; ++kk){
      const int kb = (w*4 + kk)*32;
      s16x8 af = *(const s16x8*)&As[fr*512 + kb + fko];
      s16x8 b0 = *(const s16x8*)&Hs[fr*512 + kb + fko];
      s16x8 b1 = *(const s16x8*)&Hs[(16 + fr)*512 + kb + fko];
      acc0 = __builtin_amdgcn_mfma_f32_16x16x32_bf16(af, b0, acc0, 0, 0, 0);
      acc1 = __builtin_amdgcn_mfma_f32_16x16x32_bf16(af, b1, acc1, 0, 0, 0);
    }
    #pragma unroll
    for (int r = 0; r < 4; ++r){
      Cp[w][(l >> 4)*4 + r][fr]      = acc0[r];
      Cp[w][(l >> 4)*4 + r][16 + fr] = acc1[r];
    }
  }
  __syncthreads();
  if (tid < 128){
    const int dl = tid >> 5, b = tid & 31;
    const int d = blk*4 + dl;
    const int bd = b*512 + d;
    float gv[4];
    #pragma unroll
    for (int g = 0; g < 4; ++g)
      gv[g] = Cp[0][dl*4 + g][b] + Cp[1][dl*4 + g][b] + Cp[2][dl*4 + g][b] + Cp[3][dl*4 + g][b];
    const float4 x4 = *(const float4*)&X[((size_t)(t*BB + b))*2048 + d*4];
    const float4 g4 = *(const float4*)&bgs[d*4];
    const float iv = gv[0] + x4.x + g4.x;
    const float fv = gv[1] + x4.y + g4.y;
    const float gg = gv[2] + x4.z + g4.z;
    const float ov = gv[3] + x4.w + g4.w;
    const float cn = sigm(fv)*c_st[bd] + sigm(iv)*tanhf(gg);
    const float hd = sigm(ov)*tanhf(cn);
    c_st[bd] = cn;
    hist[(size_t)(t + 1)*16384 + bd] = hd;
    const u16 hb = f2bf(hd);
    histb[(size_t)(t + 1)*16384 + bd] = hb;
    ccatb[((size_t)(t*BB + b))*1536 + d] = hb;
  }
}

// ---------------- bulk QE/QD ----------------
__global__ __launch_bounds__(256) void k_bulkq(
    const u16* __restrict__ Hb, const u16* __restrict__ encWb, const u16* __restrict__ decWb,
    float* __restrict__ qe_all, float* __restrict__ qd_all)
{
  __shared__ __align__(16) char smem[34816];
  const int e = blockIdx.x;           // 0..39
  const int which = e / 20;
  const int e2 = e % 20;
  const int mt = e2 % 5, nt = e2 / 5;
  gemm_tile<0>(Hb, which ? decWb : encWb, which ? qd_all : qe_all,
               nullptr, nullptr, 512, mt, nt, 512, 0, smem);
}

// ---------------- bulk attention: 640 enc rows + 640 dec rows ----------------
__global__ __launch_bounds__(256) void k_attn(
    const u16* __restrict__ heb, const float* __restrict__ hist,
    const float* __restrict__ qe_all, const float* __restrict__ qd_all,
    const float* __restrict__ puW,
    u16* __restrict__ ccatb, float* __restrict__ aeall,
    float* __restrict__ psE, float* __restrict__ psD)
{
  __shared__ float hcur[512];
  __shared__ float qv[512];
  __shared__ float ael[SS];
  __shared__ float red[256];
  __shared__ float part[4*512];
  __shared__ float adl[TT];
  __shared__ float sdl[TT];
  __shared__ float shs[2];
  const int blk = blockIdx.x;
  const int tid = threadIdx.x;

  if (blk < 640){
    const int row = blk;
    const int t = row >> 5, b = row & 31;
    const float* hsrc = hist + (size_t)(t + 1)*16384 + b*512;
    const float* qsrc = qe_all + (size_t)row*512;
    hcur[tid] = hsrc[tid]; hcur[tid + 256] = hsrc[tid + 256];
    qv[tid] = qsrc[tid];   qv[tid + 256] = qsrc[tid + 256];
    __syncthreads();
    for (int pass = 0; pass < 7; ++pass){
      const int s = pass*64 + (tid >> 2);
      if (s < SS){
        const u16* gp = heb + ((size_t)(b*SS + s))*512 + (tid & 3)*128;
        const float* hp = qv + (tid & 3)*128;
        float p = 0.0f;
        #pragma unroll 4
        for (int k8 = 0; k8 < 128; k8 += 8){
          s16x8 g8 = *(const s16x8*)&gp[k8];
          #pragma unroll
          for (int q = 0; q < 8; ++q) p += bf2f((u16)g8[q])*hp[k8 + q];
        }
        p += __shfl_xor(p, 1); p += __shfl_xor(p, 2);
        if ((tid & 3) == 0) ael[s] = p;
      }
    }
    __syncthreads();
    float lm = -1e30f;
    for (int s = tid; s < SS; s += 256) lm = fmaxf(lm, ael[s]);
    red[tid] = lm; __syncthreads();
    for (int st = 128; st; st >>= 1){ if (tid < st) red[tid] = fmaxf(red[tid], red[tid + st]); __syncthreads(); }
    const float M = red[0]; __syncthreads();
    float ls = 0.0f;
    for (int s = tid; s < SS; s += 256){ float p = __expf(ael[s] - M); ael[s] = p; ls += p; }
    red[tid] = ls; __syncthreads();
    for (int st = 128; st; st >>= 1){ if (tid < st) red[tid] += red[tid + st]; __syncthreads(); }
    const float inv = 1.0f/red[0];
    __syncthreads();
    {
      const int g = tid >> 6, th = tid & 63;
      const int d0 = th*8;
      float a8[8] = {};
      for (int s = g; s < SS; s += 4){
        const float a = ael[s];
        s16x8 hv = *(const s16x8*)&heb[((size_t)(b*SS + s))*512 + d0];
        #pragma unroll
        for (int q = 0; q < 8; ++q) a8[q] += a*bf2f((u16)hv[q]);
      }
      *(float4*)&part[g*512 + d0]     = float4{a8[0], a8[1], a8[2], a8[3]};
      *(float4*)&part[g*512 + d0 + 4] = float4{a8[4], a8[5], a8[6], a8[7]};
    }
    __syncthreads();
    {
      const int dd = tid*2;
      float ce0 = part[dd]     + part[512 + dd]     + part[1024 + dd]     + part[1536 + dd];
      float ce1 = part[dd + 1] + part[512 + dd + 1] + part[1024 + dd + 1] + part[1536 + dd + 1];
      ce0 *= inv; ce1 *= inv;
      *(u32*)&ccatb[(size_t)row*1536 + 512 + dd] = (u32)f2bf(ce0) | ((u32)f2bf(ce1) << 16);
      float pv = hcur[dd]*puW[dd] + hcur[dd + 1]*puW[dd + 1]
               + ce0*puW[512 + dd] + ce1*puW[512 + dd + 1];
      red[tid] = pv;
    }
    __syncthreads();
    for (int st = 128; st; st >>= 1){ if (tid < st) red[tid] += red[tid + st]; __syncthreads(); }
    if (tid == 0) psE[row] = red[0];
    for (int s = tid; s < SS; s += 256) aeall[(size_t)row*SS + s] = ael[s]*inv;
  } else {
    const int row = blk - 640;
    const int t = row >> 5, b = row & 31;
    const float* qsrc = qd_all + (size_t)row*512;
    qv[tid] = qsrc[tid]; qv[tid + 256] = qsrc[tid + 256];
    __syncthreads();
    for (int u0 = 0; u0 < t; u0 += 8){
      const int u = u0 + (tid >> 5);
      if (u < t){
        const float* hu = hist + (size_t)(u + 1)*16384 + b*512;
        float p = 0.0f;
        #pragma unroll
        for (int j = 0; j < 4; ++j){
          const int kb = (tid & 31)*4 + j*128;
          const float4 h4 = *(const float4*)&hu[kb];
          const float4 q4 = *(const float4*)&qv[kb];
          p += h4.x*q4.x + h4.y*q4.y + h4.z*q4.z + h4.w*q4.w;
        }
        p += __shfl_xor(p, 1); p += __shfl_xor(p, 2); p += __shfl_xor(p, 4);
        p += __shfl_xor(p, 8); p += __shfl_xor(p, 16);
        if ((tid & 31) == 0) sdl[u] = p;
      }
    }
    __syncthreads();
    if (tid == 0 && t > 0){
      float m2 = -1e30f;
      for (int u = 0; u < t; ++u) m2 = fmaxf(m2, sdl[u]);
      float s2 = 0.0f;
      for (int u = 0; u < t; ++u){ float p = __expf(sdl[u] - m2); adl[u] = p; s2 += p; }
      shs[0] = 1.0f/s2;
    }
    __syncthreads();
    const float invd = (t > 0) ? shs[0] : 0.0f;
    const int d0 = tid*2;
    float e0 = 0.0f, e1 = 0.0f;
    for (int u = 0; u < t; ++u){
      const float a = adl[u];
      const float* hu = hist + (size_t)(u + 1)*16384 + b*512 + d0;
      e0 += a*hu[0]; e1 += a*hu[1];
    }
    e0 *= invd; e1 *= invd;
    *(u32*)&ccatb[(size_t)row*1536 + 1024 + d0] = (u32)f2bf(e0) | ((u32)f2bf(e1) << 16);
    float pv = e0*puW[1024 + d0] + e1*puW[1024 + d0 + 1];
    red[tid] = pv; __syncthreads();
    for (int st = 128; st; st >>= 1){ if (tid < st) red[tid] += red[tid + st]; __syncthreads(); }
    if (tid == 0) psD[row] = red[0];
  }
}

// ---------------- vocab softmax (max-free, bf16 logits stride VP2) + fused scatter ----------------
__global__ __launch_bounds__(256) void k_softmax(
    const u16* __restrict__ lg, float* __restrict__ out,
    const float* __restrict__ psE, const float* __restrict__ psD, const float* __restrict__ puB,
    const int* __restrict__ src, const float* __restrict__ ae_all)
{
  const int r = blockIdx.x, tid = threadIdx.x;
  __shared__ float rs[256];
  __shared__ float sh_inv, sh_ps;
  const u16* row = lg + (size_t)r*VP2;
  float s = 0.0f;
  for (int v8 = tid*8; v8 < VV; v8 += 2048){
    uint4 pk = *(const uint4*)&row[v8];
    u32 wds[4] = {pk.x, pk.y, pk.z, pk.w};
    #pragma unroll
    for (int q = 0; q < 8; ++q)
      s += __expf(bf2f((u16)((wds[q >> 1] >> ((q & 1)*16)) & 0xffffu)));
  }
  rs[tid] = s; __syncthreads();
  for (int st = 128; st; st >>= 1){ if (tid < st) rs[tid] += rs[tid + st]; __syncthreads(); }
  if (tid == 0){
    const float ps = 1.0f/(1.0f + __expf(-(psE[r] + psD[r] + puB[0])));
    const float stot = rs[0] - __expf(bf2f(row[1]));   // exclude PAD
    sh_ps = ps;
    sh_inv = (1.0f - ps)/stot;
  }
  __syncthreads();
  const float inv = sh_inv;
  const float ps = sh_ps;
  float* orow = out + (size_t)r*VV;
  for (int v8 = tid*8; v8 < VV; v8 += 2048){
    uint4 pk = *(const uint4*)&row[v8];
    u32 wds[4] = {pk.x, pk.y, pk.z, pk.w};
    float o[8];
    #pragma unroll
    for (int q = 0; q < 8; ++q)
      o[q] = __expf(bf2f((u16)((wds[q >> 1] >> ((q & 1)*16)) & 0xffffu)))*inv;
    *(float4*)&orow[v8]     = float4{o[0], o[1], o[2], o[3]};
    *(float4*)&orow[v8 + 4] = float4{o[4], o[5], o[6], o[7]};
  }
  if (tid == 0) orow[1] = 0.0f;      // PAD masked before scatter
  __syncthreads();
  // fused copy-distribution scatter into this block's own row (L2-hot)
  const int b = r & 31;
  for (int sp = tid; sp < SS; sp += 256){
    const int v = src[sp*BB + b];
    atomicAdd(&orow[v], ae_all[(size_t)r*SS + sp]*ps);
  }
}

extern "C" void kernel_launch(void* const* d_in, const int* in_sizes, int n_in,
                              void* d_out, int out_size, void* d_ws, size_t ws_size,
                              hipStream_t stream)
{
  const int*   inputs = (const int*)  d_in[0];
  const int*   src    = (const int*)  d_in[1];
  const float* h_e    = (const float*)d_in[2];
  const float* h0     = (const float*)d_in[3];
  const float* c0     = (const float*)d_in[4];
  const float* W_emb  = (const float*)d_in[5];
  const float* W_proj = (const float*)d_in[6];
  const float* b_out  = (const float*)d_in[7];
  const float* puW    = (const float*)d_in[8];
  const float* puB    = (const float*)d_in[9];
  const float* enc_W  = (const float*)d_in[10];
  const float* dec_W  = (const float*)d_in[11];
  const float* W_ih   = (const float*)d_in[12];
  const float* W_hh   = (const float*)d_in[13];
  const float* b_ih   = (const float*)d_in[14];
  const float* b_hh   = (const float*)d_in[15];
  float* out = (float*)d_out;

  char* wp = (char*)d_ws;
  auto alloc = [&](size_t bytes) -> char* {
    char* p = wp; wp += (bytes + 255) & ~(size_t)255; return p;
  };
  // Early-dead region (reclaimed for bf16 logits after k_attn):
  u16*   Wembb = (u16*)  alloc((size_t)VP2*DD*2);     // dead after W_out GEMM
  u16*   WpT   = (u16*)  alloc(1536*512*2);           // dead after W_out GEMM
  u16*   heb   = (u16*)  alloc((size_t)SS*BB*DD*2);   // dead after k_attn
  u16*   logitsb = (u16*)Wembb;                       // 640*VP2*2 = 64.2MB <= 66.0MB above
  // Long-lived:
  u16*   Woutb = (u16*)  alloc((size_t)VP2*1536*2);
  u16*   Wihs  = (u16*)  alloc(2048*512*2);
  u16*   Whhs  = (u16*)  alloc(2048*512*2);
  u16*   encWb = (u16*)  alloc(512*512*2);
  u16*   decWb = (u16*)  alloc(512*512*2);
  float* bgs   = (float*)alloc(2048*4);
  u16*   emba  = (u16*)  alloc((size_t)TT*BB*DD*2);
  float* X     = (float*)alloc((size_t)TT*BB*2048*4);
  float* c_st  = (float*)alloc(BB*DD*4);
  float* hist  = (float*)alloc((size_t)(TT+1)*BB*DD*4);
  u16*   histb = (u16*)  alloc((size_t)(TT+1)*BB*DD*2);
  u16*   ccatb = (u16*)  alloc((size_t)TT*BB*1536*2);
  float* aeall = (float*)alloc((size_t)TT*BB*SS*4);
  float* psE   = (float*)alloc(1280*4);
  float* psD   = psE + 640;
  float* qe_all= (float*)alloc((size_t)TT*BB*DD*4);
  float* qd_all= (float*)alloc((size_t)TT*BB*DD*4);

  // mega-prep
  k_prep<<<45197, 256, 0, stream>>>(W_proj, W_ih, W_hh, b_ih, b_hh, h0, c0, enc_W, dec_W,
                                    W_emb, h_e, inputs,
                                    WpT, Wihs, Whhs, encWb, decWb, bgs, hist, histb, c_st, psE,
                                    Wembb, heb, emba);

  // X = emb @ W_ih^T
  gemm_bt<0,0><<<5*16, 256, 0, stream>>>(emba, Wihs, X, nullptr, nullptr, 512, 5, 16, 2048, 0);

  // W_out = tanh(W_emb @ W_proj): 128^2 BK=64 tiles, nt-fastest for A reuse
  gemm_bt<1,1><<<392*12, 256, 0, stream>>>(Wembb, WpT, nullptr, Woutb, nullptr, 512, 392, 12, 1536, 0);

  // sequential LSTM chain
  for (int t = 0; t < TT; ++t)
    k_lstm<<<128, 256, 0, stream>>>(Whhs, X, bgs, hist, histb, c_st, ccatb, t);

  // bulk attention
  k_bulkq<<<40, 256, 0, stream>>>(histb + 16384, encWb, decWb, qe_all, qd_all);
  k_attn<<<1280, 256, 0, stream>>>(heb, hist, qe_all, qd_all, puW, ccatb, aeall, psE, psD);

  // logits = ccat @ W_out^T + b_out (mt-fastest)
  gemm_bt<3,2><<<5*392, 256, 0, stream>>>(ccatb, Woutb, nullptr, logitsb, b_out, 1536, 5, 392, VP2, VV);

  // softmax + fused scatter
  k_softmax<<<TT*BB, 256, 0, stream>>>(logitsb, out, psE, psD, puB, src, aeall);
}